// Round 4
// baseline (6565.681 us; speedup 1.0000x reference)
//
#include <hip/hip_runtime.h>
#include <math.h>

#define NOT_FIREDf 9999.0f

// Pre-transpose conv2 weights: w2t[((ci*5+ky)*5+kx)*64 + co] = w2[(co*12+ci)*25 + ky*5+kx]
__global__ void w2_transpose_kernel(const float* __restrict__ w2, float* __restrict__ w2t) {
    int idx = blockIdx.x * 256 + threadIdx.x;
    if (idx >= 19200) return;
    int co = idx & 63;
    int r = idx >> 6;          // 0..299 = ci*25 + k
    int ci = r / 25;
    int k = r - ci * 25;
    w2t[r * 64 + co] = w2[(co * 12 + ci) * 25 + k];
}

// v1 gather: add w1 row (12 channels, contiguous in w1s [k][c] layout) into regs
#define GATHER_V1(S, Y, X) do {                                              \
    const int dy_ = py - (Y), dx_ = px - (X);                                \
    if (((unsigned)dy_ < 5u) & ((unsigned)dx_ < 5u)) {                       \
        const float* wp_ = &w1s[(dy_ * 5 + dx_) * 12];                       \
        float4 a_  = *(const float4*)(wp_);                                  \
        float4 b_  = *(const float4*)(wp_ + 4);                              \
        float4 c_  = *(const float4*)(wp_ + 8);                              \
        v1r[S][0] += a_.x; v1r[S][1] += a_.y; v1r[S][2]  += a_.z; v1r[S][3]  += a_.w; \
        v1r[S][4] += b_.x; v1r[S][5] += b_.y; v1r[S][6]  += b_.z; v1r[S][7]  += b_.w; \
        v1r[S][8] += c_.x; v1r[S][9] += c_.y; v1r[S][10] += c_.z; v1r[S][11] += c_.w; \
    } } while (0)

// v1 threshold check + pool dedup; appends PRE-DECODED event (ci<<8|py<<4|px)
#define CHECK_V1(S, Y, X) do {                                               \
    _Pragma("unroll")                                                        \
    for (int c = 0; c < 12; ++c) {                                           \
        float v_ = v1r[S][c] + b1s[c];                                       \
        if (v_ >= th) {                                                      \
            v1r[S][c] = -__builtin_inff();                                   \
            int pyp_ = (Y) >> 1, pxp_ = (X) >> 1;                            \
            int p_ = c * 144 + pyp_ * 12 + pxp_;                             \
            unsigned bit_ = 1u << (p_ & 31);                                 \
            unsigned old_ = atomicOr(&pm1[p_ >> 5], bit_);                   \
            if (!(old_ & bit_)) {                                            \
                int pos_ = atomicAdd(&cnt1[t], 1);                           \
                ev1b[t & 1][pos_] = (unsigned short)((c << 8) | (pyp_ << 4) | pxp_); \
            }                                                                \
        } else v1r[S][c] = v_;                                               \
    } } while (0)

template <int USE_T>
__launch_bounds__(256, 8)
__global__ void snn_sim_kernel(const float* __restrict__ img,
                               const float* __restrict__ w1g,
                               const float* __restrict__ b1g,
                               const float* __restrict__ b2g,
                               const float* __restrict__ w2raw,
                               const float* __restrict__ w2t,
                               const float* __restrict__ fcw,
                               const float* __restrict__ b3g,
                               float* __restrict__ out) {
    const int bimg = blockIdx.x;
    const int tid  = threadIdx.x;
    const int lane = tid & 63;
    const int wv   = tid >> 6;   // 4 waves

    __shared__ __align__(16) float w1s[300];   // transposed: [k=ky*5+kx][c]
    __shared__ float b1s[12];
    __shared__ float th_lds[80];
    __shared__ unsigned char  stin[784];       // input spike time per pixel (init only)
    __shared__ unsigned short evlist[784];     // t-sorted schedule, packed (py<<8|px)
    __shared__ unsigned short off[81];
    __shared__ unsigned int   hist[80];
    __shared__ unsigned short ev1b[2][1728];   // double-buffered pooled-l1 events (pre-decoded)
    __shared__ int            cnt1[80];        // per-step counters, never reset
    __shared__ unsigned int   pm1[54];
    __shared__ unsigned int   pm2[32];
    __shared__ unsigned int   e2list[1024];    // persistent: (t<<16) | nhwc_flat_idx
    __shared__ int            e2_cnt;

    // ---- init ----
    for (int i = tid; i < 300; i += 256) {
        int k = i / 12, c = i - k * 12;
        w1s[i] = w1g[c * 25 + k];
    }
    if (tid < 12) b1s[tid] = b1g[tid];
    if (tid < 80) {
        float xa = (0.0f - (float)tid) / 20.0f;
        th_lds[tid] = (float)exp((double)xa);            // correctly-rounded f32 exp
        hist[tid] = 0u;
        cnt1[tid] = 0;
    }
    if (tid < 54) pm1[tid] = 0u;
    if (tid < 32) pm2[tid] = 0u;
    if (tid == 0) e2_cnt = 0;
    for (int i = tid; i < 784; i += 256) {
        float p = img[bimg * 784 + i];
        p = fmaxf(p, 1e-5f);
        float lg = (float)log((double)p);                // correctly-rounded f32 log
        float s = ceilf(fmaxf(-17.452274f * lg, 0.0f));
        stin[i] = (unsigned char)(int)fminf(s, 255.0f);
    }
    __syncthreads();
    for (int i = tid; i < 784; i += 256) {
        int t = stin[i];
        if (t < 80) atomicAdd(&hist[t], 1u);
    }
    __syncthreads();
    if (tid == 0) {
        unsigned int acc = 0;
        for (int t = 0; t < 80; ++t) { off[t] = (unsigned short)acc; acc += hist[t]; }
        off[80] = (unsigned short)acc;
    }
    __syncthreads();
    if (tid < 80) {                            // deterministic pixel-order fill per t-bin
        int k = off[tid];
        for (int i = 0; i < 784; ++i)
            if ((int)stin[i] == tid) {
                int py = i / 28;
                evlist[k++] = (unsigned short)((py << 8) | (i - py * 28));
            }
    }

    // ---- register state ----
    float v1r[3][12];
#pragma unroll
    for (int s = 0; s < 3; ++s)
#pragma unroll
        for (int c = 0; c < 12; ++c) v1r[s][c] = 0.0f;
    float v2r[16];
#pragma unroll
    for (int j = 0; j < 16; ++j) v2r[j] = 0.0f;

    const int y0 = tid / 24,  x0 = tid - y0 * 24;
    const int p1i = tid + 256;
    const int y1 = p1i / 24,  x1 = p1i - y1 * 24;
    const int has2 = (tid < 64);
    const int p2i = tid + 512;
    const int y2 = p2i / 24,  x2 = p2i - y2 * 24;
    const float b2v = b2g[lane];
    const int oyb = wv * 2;                    // v2 rows owned: oyb, oyb+1

    __syncthreads();

    // ---- time loop: ONE barrier per step ----
    for (int t = 0; t < 80; ++t) {
        const float th = th_lds[t];

        // phase 1: gather input events into v1 regs, then check + pool-dedup
        {
            const int e0 = off[t], e1 = off[t + 1];
            for (int e = e0; e < e1; ++e) {
                const unsigned pk = evlist[e]; // LDS broadcast, pre-decoded
                const int py = pk >> 8;
                const int px = pk & 255;
                GATHER_V1(0, y0, x0);
                GATHER_V1(1, y1, x1);
                if (has2) GATHER_V1(2, y2, x2);
            }
        }
        CHECK_V1(0, y0, x0);
        CHECK_V1(1, y1, x1);
        if (has2) CHECK_V1(2, y2, x2);
        __syncthreads();                       // B1: ev1b[t&1]/cnt1[t] complete

        // phase 2: gather layer1 pooled events into v2 regs (mask-based windows)
        const int ne1 = cnt1[t];
        for (int e = 0; e < ne1; ++e) {
            const unsigned pk = ev1b[t & 1][e];   // LDS broadcast, pre-decoded
            const int ci = pk >> 8;
            const int py = (pk >> 4) & 15;
            const int px = pk & 15;
            const unsigned rowm = ((0x1Fu << py) >> 4) & 0xFFu;
            const unsigned rsel = (rowm >> oyb) & 3u;
            if (!rsel) continue;               // wave-uniform early-out
            const unsigned colm = ((0x1Fu << px) >> 4) & 0xFFu;
            if (USE_T) {
                const float* bp = w2t + lane + ci * 1600 + (py * 5 + px) * 64;
                if (rsel & 1u) {
                    const float* rp = bp - oyb * 320;
#pragma unroll
                    for (int j = 0; j < 8; ++j)
                        if (colm & (1u << j)) v2r[j] += rp[-(j * 64)];
                }
                if (rsel & 2u) {
                    const float* rp = bp - (oyb + 1) * 320;
#pragma unroll
                    for (int j = 0; j < 8; ++j)
                        if (colm & (1u << j)) v2r[8 + j] += rp[-(j * 64)];
                }
            } else {
                const float* wrow = w2raw + lane * 300 + ci * 25;
                if (rsel & 1u) {
                    const float* rp = wrow + (py - oyb) * 5 + px;
#pragma unroll
                    for (int j = 0; j < 8; ++j)
                        if (colm & (1u << j)) v2r[j] += rp[-j];
                }
                if (rsel & 2u) {
                    const float* rp = wrow + (py - oyb - 1) * 5 + px;
#pragma unroll
                    for (int j = 0; j < 8; ++j)
                        if (colm & (1u << j)) v2r[8 + j] += rp[-j];
                }
            }
        }
        // layer2 threshold check + pool dedup + event log
#pragma unroll
        for (int jj = 0; jj < 16; ++jj) {
            float v = v2r[jj] + b2v;
            if (v >= th) {
                v2r[jj] = -__builtin_inff();
                const int oy = oyb + (jj >> 3), ox = jj & 7;
                const int p2 = ((oy >> 1) * 4 + (ox >> 1)) * 64 + lane;  // NHWC flat
                unsigned bit = 1u << (p2 & 31);
                unsigned old = atomicOr(&pm2[p2 >> 5], bit);
                if (!(old & bit)) {
                    int pos = atomicAdd(&e2_cnt, 1);
                    e2list[pos] = ((unsigned)t << 16) | (unsigned)p2;
                }
            } else v2r[jj] = v;
        }
        // no second barrier: next step's phase 1 touches only ev1b[(t+1)&1]/cnt1[t+1]
    }
    __syncthreads();                           // e2list complete

    // ---- output layer: replay t-sorted layer2 event log (no feedback) ----
    if (tid < 10) {
        const int n2 = e2_cnt;
        const float b3v = b3g[tid];
        float v = 0.0f;
        float ot = NOT_FIREDf;
        int ptr = 0;
        for (int t = 0; t < 80; ++t) {
            float acc = 0.0f;
            while (ptr < n2 && (int)(e2list[ptr] >> 16) == t) {
                acc += fcw[(e2list[ptr] & 0xFFFFu) * 10 + tid];
                ++ptr;
            }
            v += acc + b3v;
            if (ot == NOT_FIREDf && v >= th_lds[t]) ot = (float)t;
        }
        out[bimg * 10 + tid] = ot;
    }
}

extern "C" void kernel_launch(void* const* d_in, const int* in_sizes, int n_in,
                              void* d_out, int out_size, void* d_ws, size_t ws_size,
                              hipStream_t stream) {
    const float* img = (const float*)d_in[0];
    const float* w1  = (const float*)d_in[1];
    const float* b1  = (const float*)d_in[2];
    const float* w2  = (const float*)d_in[3];
    const float* b2  = (const float*)d_in[4];
    const float* fcw = (const float*)d_in[5];
    const float* b3  = (const float*)d_in[6];
    float* out = (float*)d_out;

    const int B = in_sizes[0] / (28 * 28);

    float* w2t = (float*)d_ws;
    const int use_t = (ws_size >= 19200 * sizeof(float)) ? 1 : 0;
    if (use_t) {
        hipLaunchKernelGGL(w2_transpose_kernel, dim3(75), dim3(256), 0, stream, w2, w2t);
        hipLaunchKernelGGL(snn_sim_kernel<1>, dim3(B), dim3(256), 0, stream,
                           img, w1, b1, b2, w2, w2t, fcw, b3, out);
    } else {
        hipLaunchKernelGGL(snn_sim_kernel<0>, dim3(B), dim3(256), 0, stream,
                           img, w1, b1, b2, w2, w2t, fcw, b3, out);
    }
}

// Round 5
// 5477.632 us; speedup vs baseline: 1.1986x; 1.1986x over previous
//
#include <hip/hip_runtime.h>
#include <math.h>

#define NOT_FIREDf 9999.0f

// Pre-transpose conv2 weights: w2t[((ci*5+ky)*5+kx)*64 + co] = w2[(co*12+ci)*25 + ky*5+kx]
__global__ void w2_transpose_kernel(const float* __restrict__ w2, float* __restrict__ w2t) {
    int idx = blockIdx.x * 256 + threadIdx.x;
    if (idx >= 19200) return;
    int co = idx & 63;
    int r = idx >> 6;          // 0..299 = ci*25 + k
    int ci = r / 25;
    int k = r - ci * 25;
    w2t[r * 64 + co] = w2[(co * 12 + ci) * 25 + k];
}

// v1 gather: add w1 row (12 channels, contiguous in w1s [k][c] layout) into regs
#define GATHER_V1(S, Y, X) do {                                              \
    const int dy_ = py - (Y), dx_ = px - (X);                                \
    if (((unsigned)dy_ < 5u) & ((unsigned)dx_ < 5u)) {                       \
        const float* wp_ = &w1s[(dy_ * 5 + dx_) * 12];                       \
        float4 a_  = *(const float4*)(wp_);                                  \
        float4 b_  = *(const float4*)(wp_ + 4);                              \
        float4 c_  = *(const float4*)(wp_ + 8);                              \
        v1r[S][0] += a_.x; v1r[S][1] += a_.y; v1r[S][2]  += a_.z; v1r[S][3]  += a_.w; \
        v1r[S][4] += b_.x; v1r[S][5] += b_.y; v1r[S][6]  += b_.z; v1r[S][7]  += b_.w; \
        v1r[S][8] += c_.x; v1r[S][9] += c_.y; v1r[S][10] += c_.z; v1r[S][11] += c_.w; \
    } } while (0)

// one phase-1 input event (pk = (py<<8)|px)
#define P1EVENT(PK) do {                                                     \
    const int py = (int)((PK) >> 8);                                         \
    const int px = (int)((PK) & 255u);                                       \
    GATHER_V1(0, y0, x0);                                                    \
    GATHER_V1(1, y1, x1);                                                    \
    if (has2) GATHER_V1(2, y2, x2);                                          \
  } while (0)

// v1 threshold check + pool dedup; appends PRE-DECODED event (ci<<8|py<<4|px)
#define CHECK_V1(S, Y, X) do {                                               \
    _Pragma("unroll")                                                        \
    for (int c = 0; c < 12; ++c) {                                           \
        float v_ = v1r[S][c] + b1s[c];                                       \
        if (v_ >= th) {                                                      \
            v1r[S][c] = -__builtin_inff();                                   \
            int pyp_ = (Y) >> 1, pxp_ = (X) >> 1;                            \
            int p_ = c * 144 + pyp_ * 12 + pxp_;                             \
            unsigned bit_ = 1u << (p_ & 31);                                 \
            unsigned old_ = atomicOr(&pm1[p_ >> 5], bit_);                   \
            if (!(old_ & bit_)) {                                            \
                int pos_ = atomicAdd(&cnt1[t], 1);                           \
                ev1b[t & 1][pos_] = (unsigned short)((c << 8) | (pyp_ << 4) | pxp_); \
            }                                                                \
        } else v1r[S][c] = v_;                                               \
    } } while (0)

// one phase-2 event, fully branchless; PK is wave-uniform (readfirstlane'd)
// scalar decode/addresses on SALU; loads clamped in-bounds; fmac with 0/1 mask
#define PROC2(PK) do {                                                       \
    const unsigned ci_ = (PK) >> 8;                                          \
    const int py_ = (int)(((PK) >> 4) & 15u);                                \
    const int px_ = (int)((PK) & 15u);                                       \
    const unsigned colm_ = ((0x1Fu << px_) >> 4) & 0xFFu;                    \
    const int dy0_ = py_ - oyb;                                              \
    const int dy1_ = dy0_ - 1;                                               \
    const unsigned m0_ = ((unsigned)dy0_ < 5u) ? colm_ : 0u;                 \
    const unsigned m1_ = ((unsigned)dy1_ < 5u) ? colm_ : 0u;                 \
    const int dy0c_ = dy0_ < 0 ? 0 : (dy0_ > 4 ? 4 : dy0_);                  \
    const int dy1c_ = dy1_ < 0 ? 0 : (dy1_ > 4 ? 4 : dy1_);                  \
    const float* r0_;                                                        \
    const float* r1_;                                                        \
    if (USE_T) {                                                             \
        const float* cb_ = w2t + ci_ * 1600 + lane;                          \
        r0_ = cb_ + dy0c_ * 320; r1_ = cb_ + dy1c_ * 320;                    \
    } else {                                                                 \
        const float* cb_ = w2raw + lane * 300 + ci_ * 25;                    \
        r0_ = cb_ + dy0c_ * 5;   r1_ = cb_ + dy1c_ * 5;                      \
    }                                                                        \
    _Pragma("unroll")                                                        \
    for (int j = 0; j < 8; ++j) {                                            \
        const int dx_ = px_ - j;                                             \
        const int dxc_ = dx_ < 0 ? 0 : (dx_ > 4 ? 4 : dx_);                  \
        const int st_ = USE_T ? 64 : 1;                                      \
        const float w0_ = r0_[dxc_ * st_];                                   \
        const float w1_ = r1_[dxc_ * st_];                                   \
        const float f0_ = ((m0_ >> j) & 1u) ? 1.0f : 0.0f;                   \
        const float f1_ = ((m1_ >> j) & 1u) ? 1.0f : 0.0f;                   \
        v2r[j]     = fmaf(w0_, f0_, v2r[j]);                                 \
        v2r[8 + j] = fmaf(w1_, f1_, v2r[8 + j]);                             \
    }                                                                        \
  } while (0)

template <int USE_T>
__launch_bounds__(256, 4)
__global__ void snn_sim_kernel(const float* __restrict__ img,
                               const float* __restrict__ w1g,
                               const float* __restrict__ b1g,
                               const float* __restrict__ b2g,
                               const float* __restrict__ w2raw,
                               const float* __restrict__ w2t,
                               const float* __restrict__ fcw,
                               const float* __restrict__ b3g,
                               float* __restrict__ out) {
    const int bimg = blockIdx.x;
    const int tid  = threadIdx.x;
    const int lane = tid & 63;
    const int wv   = tid >> 6;   // 4 waves

    __shared__ __align__(16) float w1s[300];   // transposed: [k=ky*5+kx][c]
    __shared__ float b1s[12];
    __shared__ float th_lds[80];
    __shared__ unsigned char  stin[784];       // input spike time per pixel (init only)
    __shared__ unsigned short evlist[784];     // t-sorted schedule, packed (py<<8|px)
    __shared__ unsigned short off[81];
    __shared__ unsigned int   hist[80];
    __shared__ unsigned short ev1b[2][1728];   // double-buffered pooled-l1 events (pre-decoded)
    __shared__ int            cnt1[80];        // per-step counters, never reset
    __shared__ unsigned int   pm1[54];
    __shared__ unsigned int   pm2[32];
    __shared__ unsigned int   e2list[1024];    // persistent: (t<<16) | nhwc_flat_idx
    __shared__ int            e2_cnt;

    // ---- init ----
    for (int i = tid; i < 300; i += 256) {
        int k = i / 12, c = i - k * 12;
        w1s[i] = w1g[c * 25 + k];
    }
    if (tid < 12) b1s[tid] = b1g[tid];
    if (tid < 80) {
        float xa = (0.0f - (float)tid) / 20.0f;
        th_lds[tid] = (float)exp((double)xa);            // correctly-rounded f32 exp
        hist[tid] = 0u;
        cnt1[tid] = 0;
    }
    if (tid < 54) pm1[tid] = 0u;
    if (tid < 32) pm2[tid] = 0u;
    if (tid == 0) e2_cnt = 0;
    for (int i = tid; i < 784; i += 256) {
        float p = img[bimg * 784 + i];
        p = fmaxf(p, 1e-5f);
        float lg = (float)log((double)p);                // correctly-rounded f32 log
        float s = ceilf(fmaxf(-17.452274f * lg, 0.0f));
        stin[i] = (unsigned char)(int)fminf(s, 255.0f);
    }
    __syncthreads();
    for (int i = tid; i < 784; i += 256) {
        int t = stin[i];
        if (t < 80) atomicAdd(&hist[t], 1u);
    }
    __syncthreads();
    if (tid == 0) {
        unsigned int acc = 0;
        for (int t = 0; t < 80; ++t) { off[t] = (unsigned short)acc; acc += hist[t]; }
        off[80] = (unsigned short)acc;
    }
    __syncthreads();
    if (tid < 80) {                            // deterministic pixel-order fill per t-bin
        int k = off[tid];
        for (int i = 0; i < 784; ++i)
            if ((int)stin[i] == tid) {
                int py = i / 28;
                evlist[k++] = (unsigned short)((py << 8) | (i - py * 28));
            }
    }

    // ---- register state ----
    float v1r[3][12];
#pragma unroll
    for (int s = 0; s < 3; ++s)
#pragma unroll
        for (int c = 0; c < 12; ++c) v1r[s][c] = 0.0f;
    float v2r[16];
#pragma unroll
    for (int j = 0; j < 16; ++j) v2r[j] = 0.0f;

    const int y0 = tid / 24,  x0 = tid - y0 * 24;
    const int p1i = tid + 256;
    const int y1 = p1i / 24,  x1 = p1i - y1 * 24;
    const int has2 = (tid < 64);
    const int p2i = tid + 512;
    const int y2 = p2i / 24,  x2 = p2i - y2 * 24;
    const float b2v = b2g[lane];
    const int oyb = wv * 2;                    // v2 rows owned: oyb, oyb+1

    __syncthreads();

    // ---- time loop: ONE barrier per step ----
    for (int t = 0; t < 80; ++t) {
        const float th = th_lds[t];

        // phase 1: gather input events into v1 regs (unroll-4 prefetch)
        {
            const int e0 = off[t], e1t = off[t + 1];
            int e = e0;
            for (; e + 4 <= e1t; e += 4) {
                const unsigned a0 = evlist[e];
                const unsigned a1 = evlist[e + 1];
                const unsigned a2 = evlist[e + 2];
                const unsigned a3 = evlist[e + 3];
                P1EVENT(a0); P1EVENT(a1); P1EVENT(a2); P1EVENT(a3);
            }
            for (; e < e1t; ++e) { const unsigned a = evlist[e]; P1EVENT(a); }
        }
        CHECK_V1(0, y0, x0);
        CHECK_V1(1, y1, x1);
        if (has2) CHECK_V1(2, y2, x2);
        __syncthreads();                       // B1: ev1b[t&1]/cnt1[t] complete

        // phase 2: branchless scalarized gather of pooled-l1 events (unroll-2)
        {
            const int ne1 = cnt1[t];
            const unsigned short* evp = ev1b[t & 1];
            int e = 0;
            for (; e + 2 <= ne1; e += 2) {
                const unsigned pk0 = (unsigned)__builtin_amdgcn_readfirstlane((int)evp[e]);
                const unsigned pk1 = (unsigned)__builtin_amdgcn_readfirstlane((int)evp[e + 1]);
                PROC2(pk0);
                PROC2(pk1);
            }
            if (e < ne1) {
                const unsigned pk0 = (unsigned)__builtin_amdgcn_readfirstlane((int)evp[e]);
                PROC2(pk0);
            }
        }
        // layer2 threshold check + pool dedup + event log
#pragma unroll
        for (int jj = 0; jj < 16; ++jj) {
            float v = v2r[jj] + b2v;
            if (v >= th) {
                v2r[jj] = -__builtin_inff();
                const int oy = oyb + (jj >> 3), ox = jj & 7;
                const int p2 = ((oy >> 1) * 4 + (ox >> 1)) * 64 + lane;  // NHWC flat
                unsigned bit = 1u << (p2 & 31);
                unsigned old = atomicOr(&pm2[p2 >> 5], bit);
                if (!(old & bit)) {
                    int pos = atomicAdd(&e2_cnt, 1);
                    e2list[pos] = ((unsigned)t << 16) | (unsigned)p2;
                }
            } else v2r[jj] = v;
        }
        // no second barrier: next step's phase 1 touches only ev1b[(t+1)&1]/cnt1[t+1]
    }
    __syncthreads();                           // e2list complete

    // ---- output layer: replay t-sorted layer2 event log (no feedback) ----
    if (tid < 10) {
        const int n2 = e2_cnt;
        const float b3v = b3g[tid];
        float v = 0.0f;
        float ot = NOT_FIREDf;
        int ptr = 0;
        for (int t = 0; t < 80; ++t) {
            float acc = 0.0f;
            while (ptr < n2 && (int)(e2list[ptr] >> 16) == t) {
                acc += fcw[(e2list[ptr] & 0xFFFFu) * 10 + tid];
                ++ptr;
            }
            v += acc + b3v;
            if (ot == NOT_FIREDf && v >= th_lds[t]) ot = (float)t;
        }
        out[bimg * 10 + tid] = ot;
    }
}

extern "C" void kernel_launch(void* const* d_in, const int* in_sizes, int n_in,
                              void* d_out, int out_size, void* d_ws, size_t ws_size,
                              hipStream_t stream) {
    const float* img = (const float*)d_in[0];
    const float* w1  = (const float*)d_in[1];
    const float* b1  = (const float*)d_in[2];
    const float* w2  = (const float*)d_in[3];
    const float* b2  = (const float*)d_in[4];
    const float* fcw = (const float*)d_in[5];
    const float* b3  = (const float*)d_in[6];
    float* out = (float*)d_out;

    const int B = in_sizes[0] / (28 * 28);

    float* w2t = (float*)d_ws;
    const int use_t = (ws_size >= 19200 * sizeof(float)) ? 1 : 0;
    if (use_t) {
        hipLaunchKernelGGL(w2_transpose_kernel, dim3(75), dim3(256), 0, stream, w2, w2t);
        hipLaunchKernelGGL(snn_sim_kernel<1>, dim3(B), dim3(256), 0, stream,
                           img, w1, b1, b2, w2, w2t, fcw, b3, out);
    } else {
        hipLaunchKernelGGL(snn_sim_kernel<0>, dim3(B), dim3(256), 0, stream,
                           img, w1, b1, b2, w2, w2t, fcw, b3, out);
    }
}

// Round 6
// 4951.572 us; speedup vs baseline: 1.3260x; 1.1062x over previous
//
#include <hip/hip_runtime.h>
#include <math.h>

#define NOT_FIREDf 9999.0f
typedef float f32x2 __attribute__((ext_vector_type(2)));

// packed f32x2 add (bit-exact element-wise IEEE add, 1 inst for 2 adds)
#define PKADD(ACC, W) asm("v_pk_add_f32 %0, %0, %1" : "+v"(ACC) : "v"(W))

// Zero-padded conv2 weights in d_ws:
// w2p[((ci*5 + dy)*19 + rx)*64 + co] = (rx-7 in [0,5)) ? w2[(co*12+ci)*25 + dy*5 + (rx-7)] : 0
// plus a 19*64 zero row at w2p + 72960.
__global__ void w2_pad_kernel(const float* __restrict__ w2, float* __restrict__ w2p) {
    int idx = blockIdx.x * 256 + threadIdx.x;
    if (idx >= 74176) return;
    if (idx >= 72960) { w2p[idx] = 0.0f; return; }
    int co = idx & 63;
    int r = idx >> 6;            // ci*95 + dy*19 + rx
    int rx = r % 19;
    int q = r / 19;
    int dy = q % 5;
    int ci = q / 5;
    int dx = rx - 7;
    w2p[idx] = ((unsigned)dx < 5u) ? w2[(co * 12 + ci) * 25 + dy * 5 + dx] : 0.0f;
}

// v1 gather: 6 pk-adds of one w1 row (12 ch) into reg pairs
#define GATHER_V1(S, Y, X) do {                                              \
    const int dy_ = py - (Y), dx_ = px - (X);                                \
    if (((unsigned)dy_ < 5u) & ((unsigned)dx_ < 5u)) {                       \
        const f32x2* wp_ = (const f32x2*)&w1s[(dy_ * 5 + dx_) * 12];         \
        PKADD(v1r[S][0], wp_[0]); PKADD(v1r[S][1], wp_[1]);                  \
        PKADD(v1r[S][2], wp_[2]); PKADD(v1r[S][3], wp_[3]);                  \
        PKADD(v1r[S][4], wp_[4]); PKADD(v1r[S][5], wp_[5]);                  \
    } } while (0)

#define P1EVENT(PK) do {                                                     \
    const int py = (int)((PK) >> 8);                                         \
    const int px = (int)((PK) & 255u);                                       \
    GATHER_V1(0, y0, x0);                                                    \
    GATHER_V1(1, y1, x1);                                                    \
    if (has2) GATHER_V1(2, y2, x2);                                          \
  } while (0)

// stepwise bias pk-add + max-screen; exact per-channel pass only on crossing
#define CHECK_V1G(S, Y, X) do {                                              \
    PKADD(v1r[S][0], b1p[0]); PKADD(v1r[S][1], b1p[1]);                      \
    PKADD(v1r[S][2], b1p[2]); PKADD(v1r[S][3], b1p[3]);                      \
    PKADD(v1r[S][4], b1p[4]); PKADD(v1r[S][5], b1p[5]);                      \
    float m_ = fmaxf(fmaxf(fmaxf(v1r[S][0].x, v1r[S][0].y),                  \
                           fmaxf(v1r[S][1].x, v1r[S][1].y)),                 \
                     fmaxf(fmaxf(v1r[S][2].x, v1r[S][2].y),                  \
                           fmaxf(v1r[S][3].x, v1r[S][3].y)));                \
    m_ = fmaxf(m_, fmaxf(fmaxf(v1r[S][4].x, v1r[S][4].y),                    \
                         fmaxf(v1r[S][5].x, v1r[S][5].y)));                  \
    if (m_ >= th) {                                                          \
        _Pragma("unroll")                                                    \
        for (int jj = 0; jj < 6; ++jj) {                                     \
            _Pragma("unroll")                                                \
            for (int el = 0; el < 2; ++el) {                                 \
                const float v_ = el ? v1r[S][jj].y : v1r[S][jj].x;           \
                if (v_ >= th) {                                              \
                    if (el) v1r[S][jj].y = -__builtin_inff();                \
                    else    v1r[S][jj].x = -__builtin_inff();                \
                    const int c_ = jj * 2 + el;                              \
                    const int pyp_ = (Y) >> 1, pxp_ = (X) >> 1;              \
                    const int p_ = c_ * 144 + pyp_ * 12 + pxp_;              \
                    const unsigned bit_ = 1u << (p_ & 31);                   \
                    const unsigned old_ = atomicOr(&pm1[p_ >> 5], bit_);     \
                    if (!(old_ & bit_)) {                                    \
                        const int pos_ = atomicAdd(&cnt1[t], 1);             \
                        ev1b[t & 1][pos_] =                                  \
                            (unsigned short)((c_ << 8) | (pyp_ << 4) | pxp_);\
                    }                                                        \
                }                                                            \
            }                                                                \
        }                                                                    \
    } } while (0)

template <int USE_T>
__global__ void __launch_bounds__(256) __attribute__((amdgpu_waves_per_eu(4, 4)))
snn_sim_kernel(const float* __restrict__ img,
               const float* __restrict__ w1g,
               const float* __restrict__ b1g,
               const float* __restrict__ b2g,
               const float* __restrict__ w2raw,
               const float* __restrict__ w2p,
               const float* __restrict__ fcw,
               const float* __restrict__ b3g,
               float* __restrict__ out) {
    const int bimg = blockIdx.x;
    const int tid  = threadIdx.x;
    const int lane = tid & 63;
    const int wv   = tid >> 6;   // 4 waves
    const int oyb_s = __builtin_amdgcn_readfirstlane(wv) * 2;   // wave-uniform SGPR

    __shared__ __align__(16) float w1s[300];   // transposed: [k=ky*5+kx][c]
    __shared__ float b1s[12];
    __shared__ float th_lds[80];
    __shared__ unsigned char  stin[784];
    __shared__ unsigned short evlist[784];     // t-sorted schedule, packed (py<<8|px)
    __shared__ unsigned short off[81];
    __shared__ unsigned int   hist[80];
    __shared__ unsigned short ev1b[2][1728];   // double-buffered pooled-l1 events
    __shared__ int            cnt1[80];        // per-step counters, never reset
    __shared__ unsigned int   pm1[54];
    __shared__ unsigned int   pm2[32];
    __shared__ unsigned int   e2list[1024];    // persistent: (t<<16) | nhwc_flat_idx
    __shared__ int            e2_cnt;

    // ---- init ----
    for (int i = tid; i < 300; i += 256) {
        int k = i / 12, c = i - k * 12;
        w1s[i] = w1g[c * 25 + k];
    }
    if (tid < 12) b1s[tid] = b1g[tid];
    if (tid < 80) {
        float xa = (0.0f - (float)tid) / 20.0f;
        th_lds[tid] = (float)exp((double)xa);            // correctly-rounded f32 exp
        hist[tid] = 0u;
        cnt1[tid] = 0;
    }
    if (tid < 54) pm1[tid] = 0u;
    if (tid < 32) pm2[tid] = 0u;
    if (tid == 0) e2_cnt = 0;
    for (int i = tid; i < 784; i += 256) {
        float p = img[bimg * 784 + i];
        p = fmaxf(p, 1e-5f);
        float lg = (float)log((double)p);                // correctly-rounded f32 log
        float s = ceilf(fmaxf(-17.452274f * lg, 0.0f));
        stin[i] = (unsigned char)(int)fminf(s, 255.0f);
    }
    __syncthreads();
    for (int i = tid; i < 784; i += 256) {
        int t = stin[i];
        if (t < 80) atomicAdd(&hist[t], 1u);
    }
    __syncthreads();
    if (tid == 0) {
        unsigned int acc = 0;
        for (int t = 0; t < 80; ++t) { off[t] = (unsigned short)acc; acc += hist[t]; }
        off[80] = (unsigned short)acc;
    }
    __syncthreads();
    if (tid < 80) {                            // deterministic pixel-order fill per t-bin
        int k = off[tid];
        for (int i = 0; i < 784; ++i)
            if ((int)stin[i] == tid) {
                int py = i / 28;
                evlist[k++] = (unsigned short)((py << 8) | (i - py * 28));
            }
    }
    __syncthreads();

    // ---- register state ----
    f32x2 v1r[3][6];
#pragma unroll
    for (int s = 0; s < 3; ++s)
#pragma unroll
        for (int j = 0; j < 6; ++j) v1r[s][j] = (f32x2){0.0f, 0.0f};
    f32x2 v2r2[8];                             // .x = row oyb, .y = row oyb+1, col j, co=lane
#pragma unroll
    for (int j = 0; j < 8; ++j) v2r2[j] = (f32x2){0.0f, 0.0f};

    f32x2 b1p[6];
#pragma unroll
    for (int j = 0; j < 6; ++j) b1p[j] = (f32x2){b1s[j * 2], b1s[j * 2 + 1]};
    const float b2v = b2g[lane];
    const f32x2 b2p = (f32x2){b2v, b2v};
    const float* zrow = w2p + 72960;

    const int y0 = tid / 24,  x0 = tid - y0 * 24;
    const int p1i = tid + 256;
    const int y1 = p1i / 24,  x1 = p1i - y1 * 24;
    const int has2 = (tid < 64);
    const int p2i = tid + 512;
    const int y2 = p2i / 24,  x2 = p2i - y2 * 24;

    // ---- time loop: ONE barrier per step ----
    for (int t = 0; t < 80; ++t) {
        const float th = th_lds[t];

        // phase 1: gather input events into v1 reg pairs (unroll-4 prefetch)
        {
            const int e0 = off[t], e1t = off[t + 1];
            int e = e0;
            for (; e + 4 <= e1t; e += 4) {
                const unsigned a0 = evlist[e];
                const unsigned a1 = evlist[e + 1];
                const unsigned a2 = evlist[e + 2];
                const unsigned a3 = evlist[e + 3];
                P1EVENT(a0); P1EVENT(a1); P1EVENT(a2); P1EVENT(a3);
            }
            for (; e < e1t; ++e) { const unsigned a = evlist[e]; P1EVENT(a); }
        }
        CHECK_V1G(0, y0, x0);
        CHECK_V1G(1, y1, x1);
        if (has2) CHECK_V1G(2, y2, x2);
        __syncthreads();                       // B1: ev1b[t&1]/cnt1[t] complete

        // phase 2: pooled-l1 events -> v2 (scalar decode; zero-padded weights)
        {
            const int ne1 = cnt1[t];
            const unsigned short* evp = ev1b[t & 1];
            for (int e = 0; e < ne1; ++e) {
                const int pk = __builtin_amdgcn_readfirstlane((int)evp[e]);
                const int dy0 = ((pk >> 4) & 15) - oyb_s;
                if ((unsigned)dy0 >= 6u) continue;          // scalar branch
                const int ci = pk >> 8;
                const int px = pk & 15;
                if (USE_T) {
                    const float* r0 = (dy0 <= 4) ? (w2p + (ci * 5 + dy0) * 1216) : zrow;
                    const float* r1 = (dy0 >= 1) ? (w2p + (ci * 5 + dy0 - 1) * 1216) : zrow;
                    const float* q0 = r0 + (px + 7) * 64 + lane;
                    const float* q1 = r1 + (px + 7) * 64 + lane;
#pragma unroll
                    for (int j = 0; j < 8; ++j) {           // 16 loads + 16 adds, no masks
                        v2r2[j].x += q0[-(j * 64)];
                        v2r2[j].y += q1[-(j * 64)];
                    }
                } else {
                    const int dy1 = dy0 - 1;
                    const unsigned colm = ((0x1Fu << px) >> 4) & 0xFFu;
                    const unsigned m0 = ((unsigned)dy0 < 5u) ? colm : 0u;
                    const unsigned m1 = ((unsigned)dy1 < 5u) ? colm : 0u;
                    const int dy0c = dy0 < 0 ? 0 : (dy0 > 4 ? 4 : dy0);
                    const int dy1c = dy1 < 0 ? 0 : (dy1 > 4 ? 4 : dy1);
                    const float* cb = w2raw + lane * 300 + ci * 25;
                    const float* r0 = cb + dy0c * 5;
                    const float* r1 = cb + dy1c * 5;
#pragma unroll
                    for (int j = 0; j < 8; ++j) {
                        const int dx = px - j;
                        const int dxc = dx < 0 ? 0 : (dx > 4 ? 4 : dx);
                        v2r2[j].x = fmaf(r0[dxc], ((m0 >> j) & 1u) ? 1.0f : 0.0f, v2r2[j].x);
                        v2r2[j].y = fmaf(r1[dxc], ((m1 >> j) & 1u) ? 1.0f : 0.0f, v2r2[j].y);
                    }
                }
            }
        }
        // layer2: stepwise bias pk-add + max-screen + rare exact pass
        {
            PKADD(v2r2[0], b2p); PKADD(v2r2[1], b2p);
            PKADD(v2r2[2], b2p); PKADD(v2r2[3], b2p);
            PKADD(v2r2[4], b2p); PKADD(v2r2[5], b2p);
            PKADD(v2r2[6], b2p); PKADD(v2r2[7], b2p);
            float m2 = fmaxf(fmaxf(fmaxf(v2r2[0].x, v2r2[0].y), fmaxf(v2r2[1].x, v2r2[1].y)),
                             fmaxf(fmaxf(v2r2[2].x, v2r2[2].y), fmaxf(v2r2[3].x, v2r2[3].y)));
            m2 = fmaxf(m2, fmaxf(fmaxf(fmaxf(v2r2[4].x, v2r2[4].y), fmaxf(v2r2[5].x, v2r2[5].y)),
                                 fmaxf(fmaxf(v2r2[6].x, v2r2[6].y), fmaxf(v2r2[7].x, v2r2[7].y))));
            if (m2 >= th) {
#pragma unroll
                for (int j = 0; j < 8; ++j) {
#pragma unroll
                    for (int el = 0; el < 2; ++el) {
                        const float v = el ? v2r2[j].y : v2r2[j].x;
                        if (v >= th) {
                            if (el) v2r2[j].y = -__builtin_inff();
                            else    v2r2[j].x = -__builtin_inff();
                            const int oy = oyb_s + el;
                            const int p2 = ((oy >> 1) * 4 + (j >> 1)) * 64 + lane;  // NHWC flat
                            const unsigned bit = 1u << (p2 & 31);
                            const unsigned old = atomicOr(&pm2[p2 >> 5], bit);
                            if (!(old & bit)) {
                                const int pos = atomicAdd(&e2_cnt, 1);
                                e2list[pos] = ((unsigned)t << 16) | (unsigned)p2;
                            }
                        }
                    }
                }
            }
        }
        // no second barrier: next step's phase 1 touches only ev1b[(t+1)&1]/cnt1[t+1]
    }
    __syncthreads();                           // e2list complete

    // ---- output layer: replay t-sorted layer2 event log (no feedback) ----
    if (tid < 10) {
        const int n2 = e2_cnt;
        const float b3v = b3g[tid];
        float v = 0.0f;
        float ot = NOT_FIREDf;
        int ptr = 0;
        for (int t = 0; t < 80; ++t) {
            float acc = 0.0f;
            while (ptr < n2 && (int)(e2list[ptr] >> 16) == t) {
                acc += fcw[(e2list[ptr] & 0xFFFFu) * 10 + tid];
                ++ptr;
            }
            v += acc + b3v;
            if (ot == NOT_FIREDf && v >= th_lds[t]) ot = (float)t;
        }
        out[bimg * 10 + tid] = ot;
    }
}

extern "C" void kernel_launch(void* const* d_in, const int* in_sizes, int n_in,
                              void* d_out, int out_size, void* d_ws, size_t ws_size,
                              hipStream_t stream) {
    const float* img = (const float*)d_in[0];
    const float* w1  = (const float*)d_in[1];
    const float* b1  = (const float*)d_in[2];
    const float* w2  = (const float*)d_in[3];
    const float* b2  = (const float*)d_in[4];
    const float* fcw = (const float*)d_in[5];
    const float* b3  = (const float*)d_in[6];
    float* out = (float*)d_out;

    const int B = in_sizes[0] / (28 * 28);

    float* w2p = (float*)d_ws;
    const int use_t = (ws_size >= 74176u * sizeof(float)) ? 1 : 0;
    if (use_t) {
        hipLaunchKernelGGL(w2_pad_kernel, dim3(290), dim3(256), 0, stream, w2, w2p);
        hipLaunchKernelGGL(snn_sim_kernel<1>, dim3(B), dim3(256), 0, stream,
                           img, w1, b1, b2, w2, w2p, fcw, b3, out);
    } else {
        hipLaunchKernelGGL(snn_sim_kernel<0>, dim3(B), dim3(256), 0, stream,
                           img, w1, b1, b2, w2, w2p, fcw, b3, out);
    }
}